// Round 4
// baseline (1180.858 us; speedup 1.0000x reference)
//
#include <hip/hip_runtime.h>

typedef unsigned short u16;
typedef __attribute__((ext_vector_type(8))) short short8;
typedef __attribute__((ext_vector_type(4))) float f32x4;

#define MFMA16(a, b, c) __builtin_amdgcn_mfma_f32_16x16x32_bf16((a), (b), (c), 0, 0, 0)

constexpr int Bb = 2, Ss = 4096, Tt = 4096, Dd = 512;
constexpr int BM = 64, BN = 64, TP = 4;
constexpr int TPART = Tt / TP;    // 1024
constexpr int TCH = TPART / BN;   // 16 T-chunks per partition
constexpr int NSTAGE = TCH * 8;   // 4 QK chunks + 4 PV chunks per T-chunk

// ---- workspace layout (bytes) ----
constexpr size_t SZ_BF = (size_t)Bb * Ss * Dd * 2;  // 8,388,608 B
constexpr size_t O_QH   = 0;
constexpr size_t O_QL   = O_QH + SZ_BF;
constexpr size_t O_D2TH = O_QL + SZ_BF;
constexpr size_t O_D2TL = O_D2TH + SZ_BF;
constexpr size_t O_D3T  = O_D2TL + SZ_BF;
constexpr size_t O_D4T  = O_D3T + SZ_BF;
constexpr size_t O_CTX  = O_D4T + (size_t)512 * 512 * 2;
constexpr size_t O_OP   = O_CTX + SZ_BF;
constexpr size_t O_MP   = O_OP + (size_t)TP * SZ_BF;
constexpr size_t O_LP   = O_MP + (size_t)TP * Bb * Ss * 4;

__device__ __forceinline__ u16 f2bf(float x) {
  union { float f; unsigned u; } v; v.f = x;
  unsigned r = v.u + 0x7fffu + ((v.u >> 16) & 1u);  // RNE
  return (u16)(r >> 16);
}
__device__ __forceinline__ float bf2f(u16 h) {
  union { unsigned u; float f; } v; v.u = ((unsigned)h) << 16;
  return v.f;
}

// ---- fused prep: d1 hi/lo split + transposes of d2 (hi+lo), d3, d4 (hi) ----
__device__ __forceinline__ void transpose_sp(const float* __restrict__ in,
                                             u16* __restrict__ outh,
                                             u16* __restrict__ outl, int R, int C,
                                             int bx, int by, int bz,
                                             int tx, int ty, float* tile) {
  const float* inb = in + (size_t)bz * R * C;
  const int x = bx * 32 + tx;
  const int y0 = by * 32;
  for (int j = ty; j < 32; j += 8)
    tile[j * 33 + tx] = inb[(size_t)(y0 + j) * C + x];
  __syncthreads();
  const size_t ob = (size_t)bz * C * R;
  for (int j = ty; j < 32; j += 8) {
    float v = tile[tx * 33 + j];
    size_t oi = ob + (size_t)(bx * 32 + j) * R + (y0 + tx);
    u16 h = f2bf(v);
    outh[oi] = h;
    if (outl) outl[oi] = f2bf(v - bf2f(h));
  }
}

__global__ void prep_kernel(const float* __restrict__ d1, const float* __restrict__ d2,
                            const float* __restrict__ d3, const float* __restrict__ d4,
                            u16* __restrict__ qh, u16* __restrict__ ql,
                            u16* __restrict__ d2th, u16* __restrict__ d2tl,
                            u16* __restrict__ d3t, u16* __restrict__ d4t) {
  __shared__ float tile[32 * 33];
  const int bid = blockIdx.x;
  const int tid = threadIdx.x;
  const int tx = tid & 31, ty = tid >> 5;
  if (bid < 4096) {  // d1 elementwise f32 -> bf16 hi + lo residual
    const int i = bid * 256 + tid;
    float4 v = ((const float4*)d1)[i];
    ushort4 hh, ll;
    hh.x = f2bf(v.x); ll.x = f2bf(v.x - bf2f(hh.x));
    hh.y = f2bf(v.y); ll.y = f2bf(v.y - bf2f(hh.y));
    hh.z = f2bf(v.z); ll.z = f2bf(v.z - bf2f(hh.z));
    hh.w = f2bf(v.w); ll.w = f2bf(v.w - bf2f(hh.w));
    ((ushort4*)qh)[i] = hh;
    ((ushort4*)ql)[i] = ll;
  } else if (bid < 8192) {  // d2 [b][512][4096] -> [b][t][d] hi+lo
    const int t = bid - 4096;
    transpose_sp(d2, d2th, d2tl, 512, 4096, t & 127, (t >> 7) & 15, t >> 11, tx, ty, tile);
  } else if (bid < 12288) {  // d3 [b][4096][512] -> [b][d][t] hi
    const int t = bid - 8192;
    transpose_sp(d3, d3t, nullptr, 4096, 512, t & 15, (t >> 4) & 127, t >> 11, tx, ty, tile);
  } else {  // d4 [512][512] -> [n][k] hi
    const int t = bid - 12288;
    transpose_sp(d4, d4t, nullptr, 512, 512, t & 15, t >> 4, 0, tx, ty, tile);
  }
}

// ---- flash attention partial, single-barrier double-buffered pipeline ----
// grid (Ss/BM=64, TP, Bb), block 256 (4 waves; wave w owns Q-rows w*16..w*16+15)
__global__ __launch_bounds__(256, 2)
void flash_part_kernel(const u16* __restrict__ qh_g,
                       const u16* __restrict__ ql_g,
                       const u16* __restrict__ d2th,
                       const u16* __restrict__ d2tl,
                       const u16* __restrict__ d3t,
                       u16* __restrict__ opart,
                       float* __restrict__ mpart,
                       float* __restrict__ lpart) {
  // stage buffer: K chunk = 64t x 128d hi (pitch 136, 8704 u16) + lo at +8704,
  //               V chunk = 128d x 64t (pitch 72, 9216 u16) -> size 17408 u16
  __shared__ u16 bufs[2][17408];
  __shared__ u16 ph[64 * 72];

  const int tid = threadIdx.x;
  const int wave = tid >> 6, lane = tid & 63, quad = lane >> 4, l15 = lane & 15;
  const int m0 = wave * 16;
  const int s0 = blockIdx.x * BM, tp = blockIdx.y, b = blockIdx.z;

  f32x4 o_acc[32];
#pragma unroll
  for (int i = 0; i < 32; i++) o_acc[i] = (f32x4){0.f, 0.f, 0.f, 0.f};
  f32x4 s_acc[4];
  float m_r[4] = {-INFINITY, -INFINITY, -INFINITY, -INFINITY};
  float l_r[4] = {0.f, 0.f, 0.f, 0.f};

  const u16* qh_row = qh_g + ((size_t)b * Ss + s0 + m0 + l15) * Dd + quad * 8;
  const u16* ql_row = ql_g + ((size_t)b * Ss + s0 + m0 + l15) * Dd + quad * 8;
  const u16* kh_b = d2th + (size_t)b * Tt * Dd;
  const u16* kl_b = d2tl + (size_t)b * Tt * Dd;
  const u16* v_b  = d3t  + (size_t)b * Dd * Tt;

  const int krow = tid >> 2, kcol = (tid & 3) * 32;  // K stage: 64 x 128
  const int vrow = tid >> 1, vcol = (tid & 1) * 32;  // V stage: 128 x 64

  // prologue: stage 0 (K chunk hi+lo, tc=0, ds=0) into bufs[0]
  {
    const int t0 = tp * TPART;
    const u16* sh = kh_b + (size_t)(t0 + krow) * Dd + kcol;
    const u16* sl = kl_b + (size_t)(t0 + krow) * Dd + kcol;
    u16* dh = &bufs[0][krow * 136 + kcol];
#pragma unroll
    for (int u = 0; u < 32; u += 8) {
      *(uint4*)(dh + u) = *(const uint4*)(sh + u);
      *(uint4*)(dh + 8704 + u) = *(const uint4*)(sl + u);
    }
  }
  __syncthreads();

  int cur = 0;
  for (int s = 0; s < NSTAGE; s++) {
    const int sub = s & 7;
    const bool has_next = (s + 1 < NSTAGE);
    const int nsub = (s + 1) & 7;
    const bool next_is_k = (nsub < 4);

    // ---- 1. prefetch next chunk into registers (issued before MFMAs) ----
    uint4 pf[8];
    if (has_next) {
      const int ntc = (s + 1) >> 3;
      const int nt0 = tp * TPART + ntc * BN;
      if (next_is_k) {
        const u16* sh = kh_b + (size_t)(nt0 + krow) * Dd + nsub * 128 + kcol;
        const u16* sl = kl_b + (size_t)(nt0 + krow) * Dd + nsub * 128 + kcol;
#pragma unroll
        for (int u = 0; u < 4; u++) {
          pf[u] = *(const uint4*)(sh + u * 8);
          pf[4 + u] = *(const uint4*)(sl + u * 8);
        }
      } else {
        const u16* sv = v_b + (size_t)((nsub - 4) * 128 + vrow) * Tt + nt0 + vcol;
#pragma unroll
        for (int u = 0; u < 4; u++) pf[u] = *(const uint4*)(sv + u * 8);
      }
    }

    // ---- 2. compute on current chunk ----
    const u16* bb = bufs[cur];
    if (sub < 4) {  // QK chunk: S += Qh*Kh + Ql*Kh + Qh*Kl over 128 d-cols
      if (sub == 0) {
#pragma unroll
        for (int nt = 0; nt < 4; nt++) s_acc[nt] = (f32x4){0.f, 0.f, 0.f, 0.f};
      }
      const int d0 = sub * 128;
      short8 ah[4], al[4];
#pragma unroll
      for (int ks = 0; ks < 4; ks++) {
        ah[ks] = *(const short8*)(qh_row + d0 + ks * 32);
        al[ks] = *(const short8*)(ql_row + d0 + ks * 32);
      }
#pragma unroll
      for (int ks = 0; ks < 4; ks++) {
        const int kk = ks * 32 + quad * 8;
#pragma unroll
        for (int nt = 0; nt < 4; nt++) {
          short8 bh = *(const short8*)&bb[(nt * 16 + l15) * 136 + kk];
          short8 bl = *(const short8*)&bb[8704 + (nt * 16 + l15) * 136 + kk];
          s_acc[nt] = MFMA16(ah[ks], bh, s_acc[nt]);
          s_acc[nt] = MFMA16(al[ks], bh, s_acc[nt]);
          s_acc[nt] = MFMA16(ah[ks], bl, s_acc[nt]);
        }
      }
      if (sub == 3) {
        // ---- online softmax (C layout: row=quad*4+r, col=nt*16+l15) ----
        float alpha[4], psum[4];
#pragma unroll
        for (int r = 0; r < 4; r++) {
          float v = fmaxf(fmaxf(s_acc[0][r], s_acc[1][r]), fmaxf(s_acc[2][r], s_acc[3][r]));
          v = fmaxf(v, __shfl_xor(v, 1));
          v = fmaxf(v, __shfl_xor(v, 2));
          v = fmaxf(v, __shfl_xor(v, 4));
          v = fmaxf(v, __shfl_xor(v, 8));
          float mn = fmaxf(m_r[r], v);
          alpha[r] = __expf(m_r[r] - mn);
          m_r[r] = mn;
          psum[r] = 0.f;
        }
#pragma unroll
        for (int nt = 0; nt < 4; nt++) {
#pragma unroll
          for (int r = 0; r < 4; r++) {
            float p = __expf(s_acc[nt][r] - m_r[r]);
            psum[r] += p;
            ph[(m0 + quad * 4 + r) * 72 + nt * 16 + l15] = f2bf(p);
          }
        }
#pragma unroll
        for (int r = 0; r < 4; r++) {
          float v = psum[r];
          v += __shfl_xor(v, 1);
          v += __shfl_xor(v, 2);
          v += __shfl_xor(v, 4);
          v += __shfl_xor(v, 8);
          l_r[r] = l_r[r] * alpha[r] + v;
        }
        bool need = (alpha[0] != 1.f) | (alpha[1] != 1.f) | (alpha[2] != 1.f) | (alpha[3] != 1.f);
        if (__any(need)) {
#pragma unroll
          for (int j = 0; j < 32; j++)
#pragma unroll
            for (int r = 0; r < 4; r++) o_acc[j][r] *= alpha[r];
        }
      }
    } else {  // PV chunk: O[nc] += P * V, 128 d-cols
      const int nc = sub - 4;
#pragma unroll
      for (int ks = 0; ks < 2; ks++) {
        const int kk = ks * 32 + quad * 8;
        short8 ap = *(const short8*)&ph[(m0 + l15) * 72 + kk];
#pragma unroll
        for (int nt = 0; nt < 8; nt++) {
          short8 bv = *(const short8*)&bb[(nt * 16 + l15) * 72 + kk];
          o_acc[nc * 8 + nt] = MFMA16(ap, bv, o_acc[nc * 8 + nt]);
        }
      }
    }

    // ---- 3. write prefetched chunk to the other buffer ----
    if (has_next) {
      if (next_is_k) {
        u16* dh = &bufs[cur ^ 1][krow * 136 + kcol];
#pragma unroll
        for (int u = 0; u < 4; u++) {
          *(uint4*)(dh + u * 8) = pf[u];
          *(uint4*)(dh + 8704 + u * 8) = pf[4 + u];
        }
      } else {
        u16* dv = &bufs[cur ^ 1][vrow * 72 + vcol];
#pragma unroll
        for (int u = 0; u < 4; u++) *(uint4*)(dv + u * 8) = pf[u];
      }
    }
    __syncthreads();
    cur ^= 1;
  }

  // ---- epilogue: unnormalized partial O (bf16) + m/l stats ----
  const size_t obase = (((size_t)tp * Bb + b) * Ss + s0) * Dd;
#pragma unroll
  for (int j = 0; j < 32; j++) {
    const int col = (j >> 3) * 128 + (j & 7) * 16 + l15;
#pragma unroll
    for (int r = 0; r < 4; r++) {
      const int row = m0 + quad * 4 + r;
      opart[obase + (size_t)row * Dd + col] = f2bf(o_acc[j][r]);
    }
  }
  if (l15 == 0) {
    const size_t sbase = ((size_t)tp * Bb + b) * Ss + s0;
#pragma unroll
    for (int r = 0; r < 4; r++) {
      const int row = m0 + quad * 4 + r;
      mpart[sbase + row] = m_r[r];
      lpart[sbase + row] = l_r[r];
    }
  }
}

// Merge TP partitions: ctx = sum_p e^{m_p-M} O_p / sum_p e^{m_p-M} l_p
__global__ void combine_kernel(const u16* __restrict__ opart,
                               const float* __restrict__ mpart,
                               const float* __restrict__ lpart,
                               u16* __restrict__ ctx) {
  const int idx = blockIdx.x * blockDim.x + threadIdx.x;  // vec8 index
  const int vpr = Dd / 8;
  const int row = idx / vpr;  // b*Ss + s
  const int dv = (idx % vpr) * 8;
  float mv[TP], mM = -INFINITY;
#pragma unroll
  for (int p = 0; p < TP; p++) {
    mv[p] = mpart[(size_t)p * Bb * Ss + row];
    mM = fmaxf(mM, mv[p]);
  }
  float w[TP], denom = 0.f;
#pragma unroll
  for (int p = 0; p < TP; p++) {
    float e = __expf(mv[p] - mM);
    w[p] = e;
    denom += e * lpart[(size_t)p * Bb * Ss + row];
  }
  const float inv = 1.0f / denom;
  float acc[8];
#pragma unroll
  for (int e = 0; e < 8; e++) acc[e] = 0.f;
#pragma unroll
  for (int p = 0; p < TP; p++) {
    uint4 raw = *(const uint4*)&opart[(size_t)p * Bb * Ss * Dd + (size_t)row * Dd + dv];
    const u16* u = (const u16*)&raw;
#pragma unroll
    for (int e = 0; e < 8; e++) acc[e] += w[p] * bf2f(u[e]);
  }
  u16 outv[8];
#pragma unroll
  for (int e = 0; e < 8; e++) outv[e] = f2bf(acc[e] * inv);
  *(uint4*)&ctx[(size_t)row * Dd + dv] = *(const uint4*)outv;
}

// out[8192,512] = ctx_bf16 @ d4 + d5 ; 128x128 tile, 256 thr, wave = 64x64
__global__ __launch_bounds__(256, 2)
void proj_kernel(const u16* __restrict__ ctx,
                 const u16* __restrict__ d4t,  // [n][k]
                 const float* __restrict__ d5,
                 float* __restrict__ out) {
  __shared__ u16 a_lds[128 * 40], b_lds[128 * 40];
  const int tid = threadIdx.x;
  const int wave = tid >> 6, lane = tid & 63, quad = lane >> 4, l15 = lane & 15;
  const int m0w = (wave & 1) * 64, n0w = (wave >> 1) * 64;
  const int bm = blockIdx.x, bn = blockIdx.y;
  f32x4 acc[4][4];
#pragma unroll
  for (int i = 0; i < 4; i++)
#pragma unroll
    for (int j = 0; j < 4; j++) acc[i][j] = (f32x4){0.f, 0.f, 0.f, 0.f};

  const int srow = tid >> 2, scol = (tid & 3) * 8;
  for (int kt = 0; kt < 16; kt++) {
    const int k0 = kt * 32;
    __syncthreads();
#pragma unroll
    for (int pass = 0; pass < 2; pass++) {
      const int row = srow + pass * 64;
      *(uint4*)&a_lds[row * 40 + scol] =
          *(const uint4*)&ctx[(size_t)(bm * 128 + row) * Dd + k0 + scol];
      *(uint4*)&b_lds[row * 40 + scol] =
          *(const uint4*)&d4t[(size_t)(bn * 128 + row) * Dd + k0 + scol];
    }
    __syncthreads();
    short8 af[4], bfr[4];
#pragma unroll
    for (int i = 0; i < 4; i++)
      af[i] = *(const short8*)&a_lds[(m0w + 16 * i + l15) * 40 + quad * 8];
#pragma unroll
    for (int j = 0; j < 4; j++)
      bfr[j] = *(const short8*)&b_lds[(n0w + 16 * j + l15) * 40 + quad * 8];
#pragma unroll
    for (int i = 0; i < 4; i++)
#pragma unroll
      for (int j = 0; j < 4; j++) acc[i][j] = MFMA16(af[i], bfr[j], acc[i][j]);
  }
#pragma unroll
  for (int j = 0; j < 4; j++) {
    const int colg = bn * 128 + n0w + 16 * j + l15;
    const float bias = d5[colg];
#pragma unroll
    for (int i = 0; i < 4; i++) {
#pragma unroll
      for (int r = 0; r < 4; r++) {
        const int rowg = bm * 128 + m0w + 16 * i + quad * 4 + r;
        out[(size_t)rowg * 512 + colg] = acc[i][j][r] + bias;
      }
    }
  }
}

extern "C" void kernel_launch(void* const* d_in, const int* in_sizes, int n_in,
                              void* d_out, int out_size, void* d_ws, size_t ws_size,
                              hipStream_t stream) {
  (void)in_sizes; (void)n_in; (void)out_size; (void)ws_size;
  const float* d1 = (const float*)d_in[0];
  const float* d2 = (const float*)d_in[1];
  const float* d3 = (const float*)d_in[2];
  const float* d4 = (const float*)d_in[3];
  const float* d5 = (const float*)d_in[4];
  float* out = (float*)d_out;
  char* ws = (char*)d_ws;

  u16* qh_g = (u16*)(ws + O_QH);
  u16* ql_g = (u16*)(ws + O_QL);
  u16* d2th = (u16*)(ws + O_D2TH);
  u16* d2tl = (u16*)(ws + O_D2TL);
  u16* d3t  = (u16*)(ws + O_D3T);
  u16* d4t  = (u16*)(ws + O_D4T);
  u16* ctx  = (u16*)(ws + O_CTX);
  u16* opart = (u16*)(ws + O_OP);
  float* mpart = (float*)(ws + O_MP);
  float* lpart = (float*)(ws + O_LP);

  prep_kernel<<<12544, 256, 0, stream>>>(d1, d2, d3, d4, qh_g, ql_g, d2th, d2tl, d3t, d4t);
  flash_part_kernel<<<dim3(Ss / BM, TP, Bb), 256, 0, stream>>>(qh_g, ql_g, d2th, d2tl, d3t,
                                                               opart, mpart, lpart);
  combine_kernel<<<(Bb * Ss * Dd / 8) / 256, 256, 0, stream>>>(opart, mpart, lpart, ctx);
  proj_kernel<<<dim3(64, 4), 256, 0, stream>>>(ctx, d4t, d5, out);
}

// Round 5
// 843.624 us; speedup vs baseline: 1.3997x; 1.3997x over previous
//
#include <hip/hip_runtime.h>

typedef unsigned short u16;
typedef __attribute__((ext_vector_type(8))) short short8;
typedef __attribute__((ext_vector_type(4))) float f32x4;

#define MFMA16(a, b, c) __builtin_amdgcn_mfma_f32_16x16x32_bf16((a), (b), (c), 0, 0, 0)
// async global->LDS DMA, 16 B/lane, dest = lds_base + lane*16
#define ASYNC_CP16(g, l)                                                        \
  __builtin_amdgcn_global_load_lds((const __attribute__((address_space(1))) void*)(g), \
                                   (__attribute__((address_space(3))) void*)(l), 16, 0, 0)

constexpr int Bb = 2, Ss = 4096, Tt = 4096, Dd = 512;
constexpr int BM = 64, BN = 64, TP = 4;
constexpr int TPART = Tt / TP;    // 1024
constexpr int TCH = TPART / BN;   // 16 T-chunks per partition
constexpr int NSTAGE = TCH * 8;   // 4 QK chunks + 4 PV chunks per T-chunk

// ---- workspace layout (bytes) ----
constexpr size_t SZ_BF = (size_t)Bb * Ss * Dd * 2;  // 8,388,608 B
constexpr size_t O_QH   = 0;
constexpr size_t O_QL   = O_QH + SZ_BF;
constexpr size_t O_D2TH = O_QL + SZ_BF;
constexpr size_t O_D2TL = O_D2TH + SZ_BF;
constexpr size_t O_D3T  = O_D2TL + SZ_BF;
constexpr size_t O_D4T  = O_D3T + SZ_BF;
constexpr size_t O_CTX  = O_D4T + (size_t)512 * 512 * 2;
constexpr size_t O_OP   = O_CTX + SZ_BF;
constexpr size_t O_MP   = O_OP + (size_t)TP * SZ_BF;
constexpr size_t O_LP   = O_MP + (size_t)TP * Bb * Ss * 4;

__device__ __forceinline__ u16 f2bf(float x) {
  union { float f; unsigned u; } v; v.f = x;
  unsigned r = v.u + 0x7fffu + ((v.u >> 16) & 1u);  // RNE
  return (u16)(r >> 16);
}
__device__ __forceinline__ float bf2f(u16 h) {
  union { unsigned u; float f; } v; v.u = ((unsigned)h) << 16;
  return v.f;
}

// ---- fused prep: d1 hi/lo split + transposes of d2 (hi+lo), d3, d4 (hi) ----
__device__ __forceinline__ void transpose_sp(const float* __restrict__ in,
                                             u16* __restrict__ outh,
                                             u16* __restrict__ outl, int R, int C,
                                             int bx, int by, int bz,
                                             int tx, int ty, float* tile) {
  const float* inb = in + (size_t)bz * R * C;
  const int x = bx * 32 + tx;
  const int y0 = by * 32;
  for (int j = ty; j < 32; j += 8)
    tile[j * 33 + tx] = inb[(size_t)(y0 + j) * C + x];
  __syncthreads();
  const size_t ob = (size_t)bz * C * R;
  for (int j = ty; j < 32; j += 8) {
    float v = tile[tx * 33 + j];
    size_t oi = ob + (size_t)(bx * 32 + j) * R + (y0 + tx);
    u16 h = f2bf(v);
    outh[oi] = h;
    if (outl) outl[oi] = f2bf(v - bf2f(h));
  }
}

__global__ void prep_kernel(const float* __restrict__ d1, const float* __restrict__ d2,
                            const float* __restrict__ d3, const float* __restrict__ d4,
                            u16* __restrict__ qh, u16* __restrict__ ql,
                            u16* __restrict__ d2th, u16* __restrict__ d2tl,
                            u16* __restrict__ d3t, u16* __restrict__ d4t) {
  __shared__ float tile[32 * 33];
  const int bid = blockIdx.x;
  const int tid = threadIdx.x;
  const int tx = tid & 31, ty = tid >> 5;
  if (bid < 4096) {  // d1 elementwise f32 -> bf16 hi + lo residual
    const int i = bid * 256 + tid;
    float4 v = ((const float4*)d1)[i];
    ushort4 hh, ll;
    hh.x = f2bf(v.x); ll.x = f2bf(v.x - bf2f(hh.x));
    hh.y = f2bf(v.y); ll.y = f2bf(v.y - bf2f(hh.y));
    hh.z = f2bf(v.z); ll.z = f2bf(v.z - bf2f(hh.z));
    hh.w = f2bf(v.w); ll.w = f2bf(v.w - bf2f(hh.w));
    ((ushort4*)qh)[i] = hh;
    ((ushort4*)ql)[i] = ll;
  } else if (bid < 8192) {  // d2 [b][512][4096] -> [b][t][d] hi+lo
    const int t = bid - 4096;
    transpose_sp(d2, d2th, d2tl, 512, 4096, t & 127, (t >> 7) & 15, t >> 11, tx, ty, tile);
  } else if (bid < 12288) {  // d3 [b][4096][512] -> [b][d][t] hi
    const int t = bid - 8192;
    transpose_sp(d3, d3t, nullptr, 4096, 512, t & 15, (t >> 4) & 127, t >> 11, tx, ty, tile);
  } else {  // d4 [512][512] -> [n][k] hi
    const int t = bid - 12288;
    transpose_sp(d4, d4t, nullptr, 512, 512, t & 15, t >> 4, 0, tx, ty, tile);
  }
}

// ---- flash attention partial: async-DMA double-buffered single-barrier pipeline ----
// grid (Ss/BM=64, TP, Bb), block 256 (4 waves; wave w owns Q-rows w*16..w*16+15).
// Stage buffers are UNPADDED (global_load_lds scatters lane*16B); bank conflicts are
// avoided by XOR-swizzling 16B column blocks by (row & 15) [K] / (row & 7) [V] on the
// SOURCE address, and XORing the same term on the read side -> 2 lanes/bank (free).
__global__ __launch_bounds__(256, 2)
void flash_part_kernel(const u16* __restrict__ qh_g,
                       const u16* __restrict__ ql_g,
                       const u16* __restrict__ d2th,
                       const u16* __restrict__ d2tl,
                       const u16* __restrict__ d3t,
                       u16* __restrict__ opart,
                       float* __restrict__ mpart,
                       float* __restrict__ lpart) {
  // buffer = K chunk (hi 64x128 @ [0,8192) u16, lo @ [8192,16384)) OR V chunk (128x64 @ [0,8192))
  __shared__ u16 bufs[2][16384];
  __shared__ u16 ph[64 * 72];

  const int tid = threadIdx.x;
  const int wave = tid >> 6, lane = tid & 63, quad = lane >> 4, l15 = lane & 15;
  const int m0 = wave * 16;
  const int s0 = blockIdx.x * BM, tp = blockIdx.y, b = blockIdx.z;

  f32x4 o_acc[32];
#pragma unroll
  for (int i = 0; i < 32; i++) o_acc[i] = (f32x4){0.f, 0.f, 0.f, 0.f};
  f32x4 s_acc[4];
  float m_r[4] = {-INFINITY, -INFINITY, -INFINITY, -INFINITY};
  float l_r[4] = {0.f, 0.f, 0.f, 0.f};

  const u16* qh_row = qh_g + ((size_t)b * Ss + s0 + m0 + l15) * Dd + quad * 8;
  const u16* ql_row = ql_g + ((size_t)b * Ss + s0 + m0 + l15) * Dd + quad * 8;
  const u16* kh_b = d2th + (size_t)b * Tt * Dd;
  const u16* kl_b = d2tl + (size_t)b * Tt * Dd;
  const u16* v_b  = d3t  + (size_t)b * Dd * Tt;

  // per-lane staging constants
  const int l4 = lane >> 4;                       // K: row-within-4 (0..3)
  const int cb16 = lane & 15;                     // K: dest col block
  const int vr8 = lane >> 3;                      // V: row-within-8 (0..7)
  const int vcb = (lane & 7) ^ (vr8 & 7);         // V: swizzled source col block

  // K chunk: 64 t-rows x 128 d-cols. wave w instr u covers rows 16w+4u..+3 (1 KB).
  auto issue_k = [&](int t0, int d0) __attribute__((always_inline)) {
    u16* base = bufs[1 ^ (0)];  // placeholder, overwritten by caller pattern below
    (void)base;
  };
  (void)issue_k;

  // prologue: stage 0 (K chunk, tc=0, d0=0) into bufs[0]
  {
    const int t0 = tp * TPART;
#pragma unroll
    for (int u = 0; u < 4; u++) {
      const int rloc = wave * 16 + u * 4 + l4;
      const int gb = cb16 ^ (u * 4 + l4);
      const u16* sh = kh_b + (size_t)(t0 + rloc) * Dd + gb * 8;
      const u16* sl = kl_b + (size_t)(t0 + rloc) * Dd + gb * 8;
      u16* ld = &bufs[0][(wave * 16 + u * 4) * 128];
      ASYNC_CP16(sh, ld);
      ASYNC_CP16(sl, ld + 8192);
    }
  }
  __syncthreads();

  int cur = 0;
  for (int s = 0; s < NSTAGE; s++) {
    const int sub = s & 7;
    const bool has_next = (s + 1 < NSTAGE);
    const int nsub = (s + 1) & 7;

    // ---- 1. issue async DMA for next chunk into the other buffer (no VGPRs held) ----
    if (has_next) {
      const int nt0 = tp * TPART + ((s + 1) >> 3) * BN;
      u16* nb = bufs[cur ^ 1];
      if (nsub < 4) {  // next is K chunk (hi+lo), d0 = nsub*128
        const int d0 = nsub * 128;
#pragma unroll
        for (int u = 0; u < 4; u++) {
          const int rloc = wave * 16 + u * 4 + l4;
          const int gb = cb16 ^ (u * 4 + l4);
          const u16* sh = kh_b + (size_t)(nt0 + rloc) * Dd + d0 + gb * 8;
          const u16* sl = kl_b + (size_t)(nt0 + rloc) * Dd + d0 + gb * 8;
          u16* ld = &nb[(wave * 16 + u * 4) * 128];
          ASYNC_CP16(sh, ld);
          ASYNC_CP16(sl, ld + 8192);
        }
      } else {  // next is V chunk: 128 d-rows x 64 t-cols, nc = nsub-4
        const int nc = nsub - 4;
#pragma unroll
        for (int u = 0; u < 4; u++) {
          const int rloc = wave * 32 + u * 8 + vr8;
          const u16* sv = v_b + (size_t)(nc * 128 + rloc) * Tt + nt0 + vcb * 8;
          u16* ld = &nb[(wave * 32 + u * 8) * 64];
          ASYNC_CP16(sv, ld);
        }
      }
    }

    // ---- 2. compute on current chunk ----
    const u16* bb = bufs[cur];
    if (sub < 4) {  // QK chunk: S += Qh*Kh + Ql*Kh + Qh*Kl over 128 d-cols
      if (sub == 0) {
#pragma unroll
        for (int nt = 0; nt < 4; nt++) s_acc[nt] = (f32x4){0.f, 0.f, 0.f, 0.f};
      }
      const int d0 = sub * 128;
      short8 ah[4], al[4];
#pragma unroll
      for (int ks = 0; ks < 4; ks++) {
        ah[ks] = *(const short8*)(qh_row + d0 + ks * 32);
        al[ks] = *(const short8*)(ql_row + d0 + ks * 32);
      }
#pragma unroll
      for (int ks = 0; ks < 4; ks++) {
#pragma unroll
        for (int nt = 0; nt < 4; nt++) {
          const int rr = nt * 16 + l15;
          const int off = rr * 128 + (((ks * 4 + quad) ^ l15)) * 8;  // swizzled read
          short8 bh = *(const short8*)&bb[off];
          short8 bl = *(const short8*)&bb[8192 + off];
          s_acc[nt] = MFMA16(ah[ks], bh, s_acc[nt]);
          s_acc[nt] = MFMA16(al[ks], bh, s_acc[nt]);
          s_acc[nt] = MFMA16(ah[ks], bl, s_acc[nt]);
        }
      }
      if (sub == 3) {
        // ---- online softmax (C layout: row=quad*4+r, col=nt*16+l15) ----
        float alpha[4], psum[4];
#pragma unroll
        for (int r = 0; r < 4; r++) {
          float v = fmaxf(fmaxf(s_acc[0][r], s_acc[1][r]), fmaxf(s_acc[2][r], s_acc[3][r]));
          v = fmaxf(v, __shfl_xor(v, 1));
          v = fmaxf(v, __shfl_xor(v, 2));
          v = fmaxf(v, __shfl_xor(v, 4));
          v = fmaxf(v, __shfl_xor(v, 8));
          float mn = fmaxf(m_r[r], v);
          alpha[r] = __expf(m_r[r] - mn);
          m_r[r] = mn;
          psum[r] = 0.f;
        }
#pragma unroll
        for (int nt = 0; nt < 4; nt++) {
#pragma unroll
          for (int r = 0; r < 4; r++) {
            float p = __expf(s_acc[nt][r] - m_r[r]);
            psum[r] += p;
            ph[(m0 + quad * 4 + r) * 72 + nt * 16 + l15] = f2bf(p);
          }
        }
#pragma unroll
        for (int r = 0; r < 4; r++) {
          float v = psum[r];
          v += __shfl_xor(v, 1);
          v += __shfl_xor(v, 2);
          v += __shfl_xor(v, 4);
          v += __shfl_xor(v, 8);
          l_r[r] = l_r[r] * alpha[r] + v;
        }
        bool need = (alpha[0] != 1.f) | (alpha[1] != 1.f) | (alpha[2] != 1.f) | (alpha[3] != 1.f);
        if (__any(need)) {
#pragma unroll
          for (int j = 0; j < 32; j++)
#pragma unroll
            for (int r = 0; r < 4; r++) o_acc[j][r] *= alpha[r];
        }
      }
    } else {  // PV chunk: O[nc] += P * V, 128 d-cols
      const int nc = sub - 4;
#pragma unroll
      for (int ks = 0; ks < 2; ks++) {
        const int kk = ks * 32 + quad * 8;
        short8 ap = *(const short8*)&ph[(m0 + l15) * 72 + kk];
#pragma unroll
        for (int nt = 0; nt < 8; nt++) {
          const int rr = nt * 16 + l15;
          const int off = rr * 64 + (((ks * 4 + quad) ^ (l15 & 7))) * 8;  // swizzled read
          short8 bv = *(const short8*)&bb[off];
          o_acc[nc * 8 + nt] = MFMA16(ap, bv, o_acc[nc * 8 + nt]);
        }
      }
    }

    // ---- 3. barrier: drains DMA (vmcnt) + separates buffer reuse ----
    __syncthreads();
    cur ^= 1;
  }

  // ---- epilogue: unnormalized partial O (bf16) + m/l stats ----
  const size_t obase = (((size_t)tp * Bb + b) * Ss + s0) * Dd;
#pragma unroll
  for (int j = 0; j < 32; j++) {
    const int col = (j >> 3) * 128 + (j & 7) * 16 + l15;
#pragma unroll
    for (int r = 0; r < 4; r++) {
      const int row = m0 + quad * 4 + r;
      opart[obase + (size_t)row * Dd + col] = f2bf(o_acc[j][r]);
    }
  }
  if (l15 == 0) {
    const size_t sbase = ((size_t)tp * Bb + b) * Ss + s0;
#pragma unroll
    for (int r = 0; r < 4; r++) {
      const int row = m0 + quad * 4 + r;
      mpart[sbase + row] = m_r[r];
      lpart[sbase + row] = l_r[r];
    }
  }
}

// Merge TP partitions: ctx = sum_p e^{m_p-M} O_p / sum_p e^{m_p-M} l_p
__global__ void combine_kernel(const u16* __restrict__ opart,
                               const float* __restrict__ mpart,
                               const float* __restrict__ lpart,
                               u16* __restrict__ ctx) {
  const int idx = blockIdx.x * blockDim.x + threadIdx.x;  // vec8 index
  const int vpr = Dd / 8;
  const int row = idx / vpr;  // b*Ss + s
  const int dv = (idx % vpr) * 8;
  float mv[TP], mM = -INFINITY;
#pragma unroll
  for (int p = 0; p < TP; p++) {
    mv[p] = mpart[(size_t)p * Bb * Ss + row];
    mM = fmaxf(mM, mv[p]);
  }
  float w[TP], denom = 0.f;
#pragma unroll
  for (int p = 0; p < TP; p++) {
    float e = __expf(mv[p] - mM);
    w[p] = e;
    denom += e * lpart[(size_t)p * Bb * Ss + row];
  }
  const float inv = 1.0f / denom;
  float acc[8];
#pragma unroll
  for (int e = 0; e < 8; e++) acc[e] = 0.f;
#pragma unroll
  for (int p = 0; p < TP; p++) {
    uint4 raw = *(const uint4*)&opart[(size_t)p * Bb * Ss * Dd + (size_t)row * Dd + dv];
    const u16* u = (const u16*)&raw;
#pragma unroll
    for (int e = 0; e < 8; e++) acc[e] += w[p] * bf2f(u[e]);
  }
  u16 outv[8];
#pragma unroll
  for (int e = 0; e < 8; e++) outv[e] = f2bf(acc[e] * inv);
  *(uint4*)&ctx[(size_t)row * Dd + dv] = *(const uint4*)outv;
}

// out[8192,512] = ctx_bf16 @ d4 + d5 ; 128x128 tile, 256 thr, wave = 64x64
__global__ __launch_bounds__(256, 2)
void proj_kernel(const u16* __restrict__ ctx,
                 const u16* __restrict__ d4t,  // [n][k]
                 const float* __restrict__ d5,
                 float* __restrict__ out) {
  __shared__ u16 a_lds[128 * 40], b_lds[128 * 40];
  const int tid = threadIdx.x;
  const int wave = tid >> 6, lane = tid & 63, quad = lane >> 4, l15 = lane & 15;
  const int m0w = (wave & 1) * 64, n0w = (wave >> 1) * 64;
  const int bm = blockIdx.x, bn = blockIdx.y;
  f32x4 acc[4][4];
#pragma unroll
  for (int i = 0; i < 4; i++)
#pragma unroll
    for (int j = 0; j < 4; j++) acc[i][j] = (f32x4){0.f, 0.f, 0.f, 0.f};

  const int srow = tid >> 2, scol = (tid & 3) * 8;
  for (int kt = 0; kt < 16; kt++) {
    const int k0 = kt * 32;
    __syncthreads();
#pragma unroll
    for (int pass = 0; pass < 2; pass++) {
      const int row = srow + pass * 64;
      *(uint4*)&a_lds[row * 40 + scol] =
          *(const uint4*)&ctx[(size_t)(bm * 128 + row) * Dd + k0 + scol];
      *(uint4*)&b_lds[row * 40 + scol] =
          *(const uint4*)&d4t[(size_t)(bn * 128 + row) * Dd + k0 + scol];
    }
    __syncthreads();
    short8 af[4], bfr[4];
#pragma unroll
    for (int i = 0; i < 4; i++)
      af[i] = *(const short8*)&a_lds[(m0w + 16 * i + l15) * 40 + quad * 8];
#pragma unroll
    for (int j = 0; j < 4; j++)
      bfr[j] = *(const short8*)&b_lds[(n0w + 16 * j + l15) * 40 + quad * 8];
#pragma unroll
    for (int i = 0; i < 4; i++)
#pragma unroll
      for (int j = 0; j < 4; j++) acc[i][j] = MFMA16(af[i], bfr[j], acc[i][j]);
  }
#pragma unroll
  for (int j = 0; j < 4; j++) {
    const int colg = bn * 128 + n0w + 16 * j + l15;
    const float bias = d5[colg];
#pragma unroll
    for (int i = 0; i < 4; i++) {
#pragma unroll
      for (int r = 0; r < 4; r++) {
        const int rowg = bm * 128 + m0w + 16 * i + quad * 4 + r;
        out[(size_t)rowg * 512 + colg] = acc[i][j][r] + bias;
      }
    }
  }
}

extern "C" void kernel_launch(void* const* d_in, const int* in_sizes, int n_in,
                              void* d_out, int out_size, void* d_ws, size_t ws_size,
                              hipStream_t stream) {
  (void)in_sizes; (void)n_in; (void)out_size; (void)ws_size;
  const float* d1 = (const float*)d_in[0];
  const float* d2 = (const float*)d_in[1];
  const float* d3 = (const float*)d_in[2];
  const float* d4 = (const float*)d_in[3];
  const float* d5 = (const float*)d_in[4];
  float* out = (float*)d_out;
  char* ws = (char*)d_ws;

  u16* qh_g = (u16*)(ws + O_QH);
  u16* ql_g = (u16*)(ws + O_QL);
  u16* d2th = (u16*)(ws + O_D2TH);
  u16* d2tl = (u16*)(ws + O_D2TL);
  u16* d3t  = (u16*)(ws + O_D3T);
  u16* d4t  = (u16*)(ws + O_D4T);
  u16* ctx  = (u16*)(ws + O_CTX);
  u16* opart = (u16*)(ws + O_OP);
  float* mpart = (float*)(ws + O_MP);
  float* lpart = (float*)(ws + O_LP);

  prep_kernel<<<12544, 256, 0, stream>>>(d1, d2, d3, d4, qh_g, ql_g, d2th, d2tl, d3t, d4t);
  flash_part_kernel<<<dim3(Ss / BM, TP, Bb), 256, 0, stream>>>(qh_g, ql_g, d2th, d2tl, d3t,
                                                               opart, mpart, lpart);
  combine_kernel<<<(Bb * Ss * Dd / 8) / 256, 256, 0, stream>>>(opart, mpart, lpart, ctx);
  proj_kernel<<<dim3(64, 4), 256, 0, stream>>>(ctx, d4t, d5, out);
}

// Round 6
// 555.689 us; speedup vs baseline: 2.1250x; 1.5182x over previous
//
#include <hip/hip_runtime.h>

typedef unsigned short u16;
typedef __attribute__((ext_vector_type(8))) short short8;
typedef __attribute__((ext_vector_type(4))) float f32x4;

#define MFMA16(a, b, c) __builtin_amdgcn_mfma_f32_16x16x32_bf16((a), (b), (c), 0, 0, 0)
// async global->LDS DMA, 16 B/lane, dest = lds_base + lane*16
#define ASYNC_CP16(g, l)                                                        \
  __builtin_amdgcn_global_load_lds((const __attribute__((address_space(1))) void*)(g), \
                                   (__attribute__((address_space(3))) void*)(l), 16, 0, 0)

constexpr int Bb = 2, Ss = 4096, Tt = 4096, Dd = 512;
constexpr int BM = 64, BN = 64, TP = 4;
constexpr int TPART = Tt / TP;    // 1024
constexpr int TCH = TPART / BN;   // 16 T-chunks per partition

// ---- workspace layout (bytes) ----
constexpr size_t SZ_BF = (size_t)Bb * Ss * Dd * 2;  // 8,388,608 B
constexpr size_t O_QH   = 0;
constexpr size_t O_QL   = O_QH + SZ_BF;
constexpr size_t O_D2TH = O_QL + SZ_BF;
constexpr size_t O_D2TL = O_D2TH + SZ_BF;
constexpr size_t O_D3T  = O_D2TL + SZ_BF;
constexpr size_t O_D4T  = O_D3T + SZ_BF;
constexpr size_t O_CTX  = O_D4T + (size_t)512 * 512 * 2;
constexpr size_t O_OP   = O_CTX + SZ_BF;
constexpr size_t O_MP   = O_OP + (size_t)TP * SZ_BF;
constexpr size_t O_LP   = O_MP + (size_t)TP * Bb * Ss * 4;

__device__ __forceinline__ u16 f2bf(float x) {
  union { float f; unsigned u; } v; v.f = x;
  unsigned r = v.u + 0x7fffu + ((v.u >> 16) & 1u);  // RNE
  return (u16)(r >> 16);
}
__device__ __forceinline__ float bf2f(u16 h) {
  union { unsigned u; float f; } v; v.u = ((unsigned)h) << 16;
  return v.f;
}

// ---- fused prep: d1 hi/lo split + transposes of d2 (hi+lo), d3, d4 (hi) ----
__device__ __forceinline__ void transpose_sp(const float* __restrict__ in,
                                             u16* __restrict__ outh,
                                             u16* __restrict__ outl, int R, int C,
                                             int bx, int by, int bz,
                                             int tx, int ty, float* tile) {
  const float* inb = in + (size_t)bz * R * C;
  const int x = bx * 32 + tx;
  const int y0 = by * 32;
  for (int j = ty; j < 32; j += 8)
    tile[j * 33 + tx] = inb[(size_t)(y0 + j) * C + x];
  __syncthreads();
  const size_t ob = (size_t)bz * C * R;
  for (int j = ty; j < 32; j += 8) {
    float v = tile[tx * 33 + j];
    size_t oi = ob + (size_t)(bx * 32 + j) * R + (y0 + tx);
    u16 h = f2bf(v);
    outh[oi] = h;
    if (outl) outl[oi] = f2bf(v - bf2f(h));
  }
}

__global__ void prep_kernel(const float* __restrict__ d1, const float* __restrict__ d2,
                            const float* __restrict__ d3, const float* __restrict__ d4,
                            u16* __restrict__ qh, u16* __restrict__ ql,
                            u16* __restrict__ d2th, u16* __restrict__ d2tl,
                            u16* __restrict__ d3t, u16* __restrict__ d4t) {
  __shared__ float tile[32 * 33];
  const int bid = blockIdx.x;
  const int tid = threadIdx.x;
  const int tx = tid & 31, ty = tid >> 5;
  if (bid < 4096) {  // d1 elementwise f32 -> bf16 hi + lo residual
    const int i = bid * 256 + tid;
    float4 v = ((const float4*)d1)[i];
    ushort4 hh, ll;
    hh.x = f2bf(v.x); ll.x = f2bf(v.x - bf2f(hh.x));
    hh.y = f2bf(v.y); ll.y = f2bf(v.y - bf2f(hh.y));
    hh.z = f2bf(v.z); ll.z = f2bf(v.z - bf2f(hh.z));
    hh.w = f2bf(v.w); ll.w = f2bf(v.w - bf2f(hh.w));
    ((ushort4*)qh)[i] = hh;
    ((ushort4*)ql)[i] = ll;
  } else if (bid < 8192) {  // d2 [b][512][4096] -> [b][t][d] hi+lo
    const int t = bid - 4096;
    transpose_sp(d2, d2th, d2tl, 512, 4096, t & 127, (t >> 7) & 15, t >> 11, tx, ty, tile);
  } else if (bid < 12288) {  // d3 [b][4096][512] -> [b][d][t] hi
    const int t = bid - 8192;
    transpose_sp(d3, d3t, nullptr, 4096, 512, t & 15, (t >> 4) & 127, t >> 11, tx, ty, tile);
  } else {  // d4 [512][512] -> [n][k] hi
    const int t = bid - 12288;
    transpose_sp(d4, d4t, nullptr, 512, 512, t & 15, t >> 4, 0, tx, ty, tile);
  }
}

// ---- flash attention partial: async-DMA double-buffered single-barrier pipeline ----
// grid (Ss/BM=64, TP, Bb), block 256 (4 waves; wave w owns Q-rows w*16..w*16+15).
// The 8 sub-stages per T-chunk are fully unrolled so ALL accumulator indices are
// compile-time (a runtime index forced o_acc into scratch in R3-R5: 2+ GB spill traffic).
// Buffer parity is compile-time too: stage sub computes on bufs[sub&1], DMAs into
// bufs[(sub+1)&1]. Bank conflicts avoided by XOR-swizzling 16B blocks on the source
// address, un-swizzled on the read side.
__global__ __launch_bounds__(256, 2)
void flash_part_kernel(const u16* __restrict__ qh_g,
                       const u16* __restrict__ ql_g,
                       const u16* __restrict__ d2th,
                       const u16* __restrict__ d2tl,
                       const u16* __restrict__ d3t,
                       u16* __restrict__ opart,
                       float* __restrict__ mpart,
                       float* __restrict__ lpart) {
  // buffer = K chunk (hi 64x128 @ [0,8192) u16, lo @ [8192,16384)) OR V chunk (128x64 @ [0,8192))
  __shared__ u16 bufs[2][16384];
  __shared__ u16 ph[64 * 72];

  const int tid = threadIdx.x;
  const int wave = tid >> 6, lane = tid & 63, quad = lane >> 4, l15 = lane & 15;
  const int m0 = wave * 16;
  const int s0 = blockIdx.x * BM, tp = blockIdx.y, b = blockIdx.z;

  f32x4 o_acc[32];
#pragma unroll
  for (int i = 0; i < 32; i++) o_acc[i] = (f32x4){0.f, 0.f, 0.f, 0.f};
  f32x4 s_acc[4];
  float m_r[4] = {-INFINITY, -INFINITY, -INFINITY, -INFINITY};
  float l_r[4] = {0.f, 0.f, 0.f, 0.f};

  const u16* qh_row = qh_g + ((size_t)b * Ss + s0 + m0 + l15) * Dd + quad * 8;
  const u16* ql_row = ql_g + ((size_t)b * Ss + s0 + m0 + l15) * Dd + quad * 8;
  const u16* kh_b = d2th + (size_t)b * Tt * Dd;
  const u16* kl_b = d2tl + (size_t)b * Tt * Dd;
  const u16* v_b  = d3t  + (size_t)b * Dd * Tt;

  // per-lane staging constants
  const int l4 = lane >> 4;                // K: row-within-4 (0..3)
  const int cb16 = lane & 15;              // K: dest col block
  const int vr8 = lane >> 3;               // V: row-within-8 (0..7)
  const int vcb = (lane & 7) ^ (vr8 & 7);  // V: swizzled source col block

  // prologue: stage 0 (K chunk, tc=0, d0=0) into bufs[0]
  {
    const int t0 = tp * TPART;
#pragma unroll
    for (int u = 0; u < 4; u++) {
      const int rloc = wave * 16 + u * 4 + l4;
      const int gb = cb16 ^ (u * 4 + l4);
      const u16* sh = kh_b + (size_t)(t0 + rloc) * Dd + gb * 8;
      const u16* sl = kl_b + (size_t)(t0 + rloc) * Dd + gb * 8;
      u16* ld = &bufs[0][(wave * 16 + u * 4) * 128];
      ASYNC_CP16(sh, ld);
      ASYNC_CP16(sl, ld + 8192);
    }
  }
  __syncthreads();

  for (int tc = 0; tc < TCH; tc++) {
#pragma unroll
    for (int sub = 0; sub < 8; sub++) {  // compile-time sub-stage id
      const bool has_next = (sub < 7) || (tc < TCH - 1);
      const int nsub = (sub + 1) & 7;
      const int ntc = (sub == 7) ? tc + 1 : tc;

      // ---- 1. issue async DMA for next chunk into the other buffer ----
      if (has_next) {
        const int nt0 = tp * TPART + ntc * BN;
        u16* nb = bufs[nsub & 1];
        if (nsub < 4) {  // next is K chunk (hi+lo), d0 = nsub*128
          const int d0 = nsub * 128;
#pragma unroll
          for (int u = 0; u < 4; u++) {
            const int rloc = wave * 16 + u * 4 + l4;
            const int gb = cb16 ^ (u * 4 + l4);
            const u16* sh = kh_b + (size_t)(nt0 + rloc) * Dd + d0 + gb * 8;
            const u16* sl = kl_b + (size_t)(nt0 + rloc) * Dd + d0 + gb * 8;
            u16* ld = &nb[(wave * 16 + u * 4) * 128];
            ASYNC_CP16(sh, ld);
            ASYNC_CP16(sl, ld + 8192);
          }
        } else {  // next is V chunk: 128 d-rows x 64 t-cols, nc = nsub-4
          const int nc = nsub - 4;
#pragma unroll
          for (int u = 0; u < 4; u++) {
            const int rloc = wave * 32 + u * 8 + vr8;
            const u16* sv = v_b + (size_t)(nc * 128 + rloc) * Tt + nt0 + vcb * 8;
            u16* ld = &nb[(wave * 32 + u * 8) * 64];
            ASYNC_CP16(sv, ld);
          }
        }
      }

      // ---- 2. compute on current chunk (buffer parity compile-time) ----
      const u16* bb = bufs[sub & 1];
      if (sub < 4) {  // QK chunk: S += Qh*Kh + Ql*Kh + Qh*Kl over 128 d-cols
        if (sub == 0) {
#pragma unroll
          for (int nt = 0; nt < 4; nt++) s_acc[nt] = (f32x4){0.f, 0.f, 0.f, 0.f};
        }
        const int d0 = sub * 128;
        short8 ah[4], al[4];
#pragma unroll
        for (int ks = 0; ks < 4; ks++) {
          ah[ks] = *(const short8*)(qh_row + d0 + ks * 32);
          al[ks] = *(const short8*)(ql_row + d0 + ks * 32);
        }
#pragma unroll
        for (int ks = 0; ks < 4; ks++) {
#pragma unroll
          for (int nt = 0; nt < 4; nt++) {
            const int rr = nt * 16 + l15;
            const int off = rr * 128 + (((ks * 4 + quad) ^ l15)) * 8;  // swizzled read
            short8 bh = *(const short8*)&bb[off];
            short8 bl = *(const short8*)&bb[8192 + off];
            s_acc[nt] = MFMA16(ah[ks], bh, s_acc[nt]);
            s_acc[nt] = MFMA16(al[ks], bh, s_acc[nt]);
            s_acc[nt] = MFMA16(ah[ks], bl, s_acc[nt]);
          }
        }
        if (sub == 3) {
          // ---- online softmax (C layout: row=quad*4+r, col=nt*16+l15) ----
          float alpha[4], psum[4];
#pragma unroll
          for (int r = 0; r < 4; r++) {
            float v = fmaxf(fmaxf(s_acc[0][r], s_acc[1][r]), fmaxf(s_acc[2][r], s_acc[3][r]));
            v = fmaxf(v, __shfl_xor(v, 1));
            v = fmaxf(v, __shfl_xor(v, 2));
            v = fmaxf(v, __shfl_xor(v, 4));
            v = fmaxf(v, __shfl_xor(v, 8));
            float mn = fmaxf(m_r[r], v);
            alpha[r] = __expf(m_r[r] - mn);
            m_r[r] = mn;
            psum[r] = 0.f;
          }
#pragma unroll
          for (int nt = 0; nt < 4; nt++) {
#pragma unroll
            for (int r = 0; r < 4; r++) {
              float p = __expf(s_acc[nt][r] - m_r[r]);
              psum[r] += p;
              ph[(m0 + quad * 4 + r) * 72 + nt * 16 + l15] = f2bf(p);
            }
          }
#pragma unroll
          for (int r = 0; r < 4; r++) {
            float v = psum[r];
            v += __shfl_xor(v, 1);
            v += __shfl_xor(v, 2);
            v += __shfl_xor(v, 4);
            v += __shfl_xor(v, 8);
            l_r[r] = l_r[r] * alpha[r] + v;
          }
          bool need = (alpha[0] != 1.f) | (alpha[1] != 1.f) | (alpha[2] != 1.f) | (alpha[3] != 1.f);
          if (__any(need)) {
#pragma unroll
            for (int j = 0; j < 32; j++)
#pragma unroll
              for (int r = 0; r < 4; r++) o_acc[j][r] *= alpha[r];
          }
        }
      } else {  // PV chunk: O[nc] += P * V, 128 d-cols; nc COMPILE-TIME
        const int nc = sub - 4;
#pragma unroll
        for (int ks = 0; ks < 2; ks++) {
          const int kk = ks * 32 + quad * 8;
          short8 ap = *(const short8*)&ph[(m0 + l15) * 72 + kk];
#pragma unroll
          for (int nt = 0; nt < 8; nt++) {
            const int rr = nt * 16 + l15;
            const int off = rr * 64 + (((ks * 4 + quad) ^ (l15 & 7))) * 8;  // swizzled read
            short8 bv = *(const short8*)&bb[off];
            o_acc[nc * 8 + nt] = MFMA16(ap, bv, o_acc[nc * 8 + nt]);
          }
        }
      }

      // ---- 3. barrier: drains DMA (vmcnt) + separates buffer reuse ----
      __syncthreads();
    }
  }

  // ---- epilogue: unnormalized partial O (bf16) + m/l stats ----
  const size_t obase = (((size_t)tp * Bb + b) * Ss + s0) * Dd;
#pragma unroll
  for (int j = 0; j < 32; j++) {
    const int col = (j >> 3) * 128 + (j & 7) * 16 + l15;
#pragma unroll
    for (int r = 0; r < 4; r++) {
      const int row = m0 + quad * 4 + r;
      opart[obase + (size_t)row * Dd + col] = f2bf(o_acc[j][r]);
    }
  }
  if (l15 == 0) {
    const size_t sbase = ((size_t)tp * Bb + b) * Ss + s0;
#pragma unroll
    for (int r = 0; r < 4; r++) {
      const int row = m0 + quad * 4 + r;
      mpart[sbase + row] = m_r[r];
      lpart[sbase + row] = l_r[r];
    }
  }
}

// Merge TP partitions: ctx = sum_p e^{m_p-M} O_p / sum_p e^{m_p-M} l_p
__global__ void combine_kernel(const u16* __restrict__ opart,
                               const float* __restrict__ mpart,
                               const float* __restrict__ lpart,
                               u16* __restrict__ ctx) {
  const int idx = blockIdx.x * blockDim.x + threadIdx.x;  // vec8 index
  const int vpr = Dd / 8;
  const int row = idx / vpr;  // b*Ss + s
  const int dv = (idx % vpr) * 8;
  float mv[TP], mM = -INFINITY;
#pragma unroll
  for (int p = 0; p < TP; p++) {
    mv[p] = mpart[(size_t)p * Bb * Ss + row];
    mM = fmaxf(mM, mv[p]);
  }
  float w[TP], denom = 0.f;
#pragma unroll
  for (int p = 0; p < TP; p++) {
    float e = __expf(mv[p] - mM);
    w[p] = e;
    denom += e * lpart[(size_t)p * Bb * Ss + row];
  }
  const float inv = 1.0f / denom;
  float acc[8];
#pragma unroll
  for (int e = 0; e < 8; e++) acc[e] = 0.f;
#pragma unroll
  for (int p = 0; p < TP; p++) {
    uint4 raw = *(const uint4*)&opart[(size_t)p * Bb * Ss * Dd + (size_t)row * Dd + dv];
    const u16* u = (const u16*)&raw;
#pragma unroll
    for (int e = 0; e < 8; e++) acc[e] += w[p] * bf2f(u[e]);
  }
  u16 outv[8];
#pragma unroll
  for (int e = 0; e < 8; e++) outv[e] = f2bf(acc[e] * inv);
  *(uint4*)&ctx[(size_t)row * Dd + dv] = *(const uint4*)outv;
}

// out[8192,512] = ctx_bf16 @ d4 + d5 ; 128x128 tile, 256 thr, wave = 64x64
__global__ __launch_bounds__(256, 2)
void proj_kernel(const u16* __restrict__ ctx,
                 const u16* __restrict__ d4t,  // [n][k]
                 const float* __restrict__ d5,
                 float* __restrict__ out) {
  __shared__ u16 a_lds[128 * 40], b_lds[128 * 40];
  const int tid = threadIdx.x;
  const int wave = tid >> 6, lane = tid & 63, quad = lane >> 4, l15 = lane & 15;
  const int m0w = (wave & 1) * 64, n0w = (wave >> 1) * 64;
  const int bm = blockIdx.x, bn = blockIdx.y;
  f32x4 acc[4][4];
#pragma unroll
  for (int i = 0; i < 4; i++)
#pragma unroll
    for (int j = 0; j < 4; j++) acc[i][j] = (f32x4){0.f, 0.f, 0.f, 0.f};

  const int srow = tid >> 2, scol = (tid & 3) * 8;
  for (int kt = 0; kt < 16; kt++) {
    const int k0 = kt * 32;
    __syncthreads();
#pragma unroll
    for (int pass = 0; pass < 2; pass++) {
      const int row = srow + pass * 64;
      *(uint4*)&a_lds[row * 40 + scol] =
          *(const uint4*)&ctx[(size_t)(bm * 128 + row) * Dd + k0 + scol];
      *(uint4*)&b_lds[row * 40 + scol] =
          *(const uint4*)&d4t[(size_t)(bn * 128 + row) * Dd + k0 + scol];
    }
    __syncthreads();
    short8 af[4], bfr[4];
#pragma unroll
    for (int i = 0; i < 4; i++)
      af[i] = *(const short8*)&a_lds[(m0w + 16 * i + l15) * 40 + quad * 8];
#pragma unroll
    for (int j = 0; j < 4; j++)
      bfr[j] = *(const short8*)&b_lds[(n0w + 16 * j + l15) * 40 + quad * 8];
#pragma unroll
    for (int i = 0; i < 4; i++)
#pragma unroll
      for (int j = 0; j < 4; j++) acc[i][j] = MFMA16(af[i], bfr[j], acc[i][j]);
  }
#pragma unroll
  for (int j = 0; j < 4; j++) {
    const int colg = bn * 128 + n0w + 16 * j + l15;
    const float bias = d5[colg];
#pragma unroll
    for (int i = 0; i < 4; i++) {
#pragma unroll
      for (int r = 0; r < 4; r++) {
        const int rowg = bm * 128 + m0w + 16 * i + quad * 4 + r;
        out[(size_t)rowg * 512 + colg] = acc[i][j][r] + bias;
      }
    }
  }
}

extern "C" void kernel_launch(void* const* d_in, const int* in_sizes, int n_in,
                              void* d_out, int out_size, void* d_ws, size_t ws_size,
                              hipStream_t stream) {
  (void)in_sizes; (void)n_in; (void)out_size; (void)ws_size;
  const float* d1 = (const float*)d_in[0];
  const float* d2 = (const float*)d_in[1];
  const float* d3 = (const float*)d_in[2];
  const float* d4 = (const float*)d_in[3];
  const float* d5 = (const float*)d_in[4];
  float* out = (float*)d_out;
  char* ws = (char*)d_ws;

  u16* qh_g = (u16*)(ws + O_QH);
  u16* ql_g = (u16*)(ws + O_QL);
  u16* d2th = (u16*)(ws + O_D2TH);
  u16* d2tl = (u16*)(ws + O_D2TL);
  u16* d3t  = (u16*)(ws + O_D3T);
  u16* d4t  = (u16*)(ws + O_D4T);
  u16* ctx  = (u16*)(ws + O_CTX);
  u16* opart = (u16*)(ws + O_OP);
  float* mpart = (float*)(ws + O_MP);
  float* lpart = (float*)(ws + O_LP);

  prep_kernel<<<12544, 256, 0, stream>>>(d1, d2, d3, d4, qh_g, ql_g, d2th, d2tl, d3t, d4t);
  flash_part_kernel<<<dim3(Ss / BM, TP, Bb), 256, 0, stream>>>(qh_g, ql_g, d2th, d2tl, d3t,
                                                               opart, mpart, lpart);
  combine_kernel<<<(Bb * Ss * Dd / 8) / 256, 256, 0, stream>>>(opart, mpart, lpart, ctx);
  proj_kernel<<<dim3(64, 4), 256, 0, stream>>>(ctx, d4t, d5, out);
}

// Round 7
// 552.689 us; speedup vs baseline: 2.1366x; 1.0054x over previous
//
#include <hip/hip_runtime.h>

typedef unsigned short u16;
typedef __attribute__((ext_vector_type(8))) short short8;
typedef __attribute__((ext_vector_type(4))) float f32x4;

#define MFMA16(a, b, c) __builtin_amdgcn_mfma_f32_16x16x32_bf16((a), (b), (c), 0, 0, 0)
// async global->LDS DMA, 16 B/lane, dest = lds_base + lane*16
#define ASYNC_CP16(g, l)                                                        \
  __builtin_amdgcn_global_load_lds((const __attribute__((address_space(1))) void*)(g), \
                                   (__attribute__((address_space(3))) void*)(l), 16, 0, 0)

constexpr int Bb = 2, Ss = 4096, Tt = 4096, Dd = 512;
constexpr int BM = 128, BN = 64, TP = 4;
constexpr int TPART = Tt / TP;    // 1024
constexpr int TCH = TPART / BN;   // 16 T-chunks per partition

// ---- workspace layout (bytes) ----
constexpr size_t SZ_BF = (size_t)Bb * Ss * Dd * 2;  // 8,388,608 B
constexpr size_t O_QH   = 0;
constexpr size_t O_QL   = O_QH + SZ_BF;
constexpr size_t O_D2TH = O_QL + SZ_BF;
constexpr size_t O_D2TL = O_D2TH + SZ_BF;
constexpr size_t O_D3T  = O_D2TL + SZ_BF;
constexpr size_t O_D4T  = O_D3T + SZ_BF;
constexpr size_t O_CTX  = O_D4T + (size_t)512 * 512 * 2;
constexpr size_t O_OP   = O_CTX + SZ_BF;
constexpr size_t O_MP   = O_OP + (size_t)TP * SZ_BF;
constexpr size_t O_LP   = O_MP + (size_t)TP * Bb * Ss * 4;

__device__ __forceinline__ u16 f2bf(float x) {
  union { float f; unsigned u; } v; v.f = x;
  unsigned r = v.u + 0x7fffu + ((v.u >> 16) & 1u);  // RNE
  return (u16)(r >> 16);
}
__device__ __forceinline__ float bf2f(u16 h) {
  union { unsigned u; float f; } v; v.u = ((unsigned)h) << 16;
  return v.f;
}

// ---- fused prep: d1 hi/lo split + transposes of d2 (hi+lo), d3, d4 (hi) ----
__device__ __forceinline__ void transpose_sp(const float* __restrict__ in,
                                             u16* __restrict__ outh,
                                             u16* __restrict__ outl, int R, int C,
                                             int bx, int by, int bz,
                                             int tx, int ty, float* tile) {
  const float* inb = in + (size_t)bz * R * C;
  const int x = bx * 32 + tx;
  const int y0 = by * 32;
  for (int j = ty; j < 32; j += 8)
    tile[j * 33 + tx] = inb[(size_t)(y0 + j) * C + x];
  __syncthreads();
  const size_t ob = (size_t)bz * C * R;
  for (int j = ty; j < 32; j += 8) {
    float v = tile[tx * 33 + j];
    size_t oi = ob + (size_t)(bx * 32 + j) * R + (y0 + tx);
    u16 h = f2bf(v);
    outh[oi] = h;
    if (outl) outl[oi] = f2bf(v - bf2f(h));
  }
}

__global__ void prep_kernel(const float* __restrict__ d1, const float* __restrict__ d2,
                            const float* __restrict__ d3, const float* __restrict__ d4,
                            u16* __restrict__ qh, u16* __restrict__ ql,
                            u16* __restrict__ d2th, u16* __restrict__ d2tl,
                            u16* __restrict__ d3t, u16* __restrict__ d4t) {
  __shared__ float tile[32 * 33];
  const int bid = blockIdx.x;
  const int tid = threadIdx.x;
  const int tx = tid & 31, ty = tid >> 5;
  if (bid < 4096) {  // d1 elementwise f32 -> bf16 hi + lo residual
    const int i = bid * 256 + tid;
    float4 v = ((const float4*)d1)[i];
    ushort4 hh, ll;
    hh.x = f2bf(v.x); ll.x = f2bf(v.x - bf2f(hh.x));
    hh.y = f2bf(v.y); ll.y = f2bf(v.y - bf2f(hh.y));
    hh.z = f2bf(v.z); ll.z = f2bf(v.z - bf2f(hh.z));
    hh.w = f2bf(v.w); ll.w = f2bf(v.w - bf2f(hh.w));
    ((ushort4*)qh)[i] = hh;
    ((ushort4*)ql)[i] = ll;
  } else if (bid < 8192) {  // d2 [b][512][4096] -> [b][t][d] hi+lo
    const int t = bid - 4096;
    transpose_sp(d2, d2th, d2tl, 512, 4096, t & 127, (t >> 7) & 15, t >> 11, tx, ty, tile);
  } else if (bid < 12288) {  // d3 [b][4096][512] -> [b][d][t] hi
    const int t = bid - 8192;
    transpose_sp(d3, d3t, nullptr, 4096, 512, t & 15, (t >> 4) & 127, t >> 11, tx, ty, tile);
  } else {  // d4 [512][512] -> [n][k] hi
    const int t = bid - 12288;
    transpose_sp(d4, d4t, nullptr, 512, 512, t & 15, t >> 4, 0, tx, ty, tile);
  }
}

// ---- flash attention partial: async-DMA double-buffered pipeline, Q in registers ----
// grid (8, 32): blockIdx.x = (b<<2)|tp  -> linear%8 pins each (tp,b) K/V partition
// (3 MB) to one XCD's L2 (locality heuristic only; correctness unaffected).
// block 512 = 8 waves; wave w owns Q-rows w*16..w*16+15 (BM=128).
// Q hi/lo fragments loaded ONCE into registers (tc-invariant, 128 VGPRs).
// Fully unrolled 8-sub-stage pipeline: compile-time acc indices & buffer parity.
__global__ __launch_bounds__(512, 2)
void flash_part_kernel(const u16* __restrict__ qh_g,
                       const u16* __restrict__ ql_g,
                       const u16* __restrict__ d2th,
                       const u16* __restrict__ d2tl,
                       const u16* __restrict__ d3t,
                       u16* __restrict__ opart,
                       float* __restrict__ mpart,
                       float* __restrict__ lpart) {
  // buffer = K chunk (hi 64x128 @ [0,8192) u16, lo @ [8192,16384)) OR V chunk (128x64 @ [0,8192))
  __shared__ u16 bufs[2][16384];
  __shared__ u16 ph[128 * 72];

  const int tid = threadIdx.x;
  const int wave = tid >> 6, lane = tid & 63, quad = lane >> 4, l15 = lane & 15;
  const int m0 = wave * 16;
  const int tp = blockIdx.x & 3, b = blockIdx.x >> 2;
  const int s0 = blockIdx.y * BM;

  f32x4 o_acc[32];
#pragma unroll
  for (int i = 0; i < 32; i++) o_acc[i] = (f32x4){0.f, 0.f, 0.f, 0.f};
  f32x4 s_acc[4];
  float m_r[4] = {-INFINITY, -INFINITY, -INFINITY, -INFINITY};
  float l_r[4] = {0.f, 0.f, 0.f, 0.f};

  const u16* kh_b = d2th + (size_t)b * Tt * Dd;
  const u16* kl_b = d2tl + (size_t)b * Tt * Dd;
  const u16* v_b  = d3t  + (size_t)b * Dd * Tt;

  // ---- Q fragments: load once, keep in registers (tc-invariant) ----
  short8 qf_h[4][4], qf_l[4][4];
  {
    const u16* qh_row = qh_g + ((size_t)b * Ss + s0 + m0 + l15) * Dd + quad * 8;
    const u16* ql_row = ql_g + ((size_t)b * Ss + s0 + m0 + l15) * Dd + quad * 8;
#pragma unroll
    for (int sub = 0; sub < 4; sub++)
#pragma unroll
      for (int ks = 0; ks < 4; ks++) {
        qf_h[sub][ks] = *(const short8*)(qh_row + sub * 128 + ks * 32);
        qf_l[sub][ks] = *(const short8*)(ql_row + sub * 128 + ks * 32);
      }
  }

  // per-lane staging constants
  const int l4 = lane >> 4;                // K: row-within-4 (0..3)
  const int cb16 = lane & 15;              // K: dest col block
  const int vr8 = lane >> 3;               // V: row-within-8 (0..7)
  const int vcb = (lane & 7) ^ (vr8 & 7);  // V: swizzled source col block

  // prologue: stage 0 (K chunk, tc=0, d0=0) into bufs[0]; 8 waves cover 64 rows
  {
    const int t0 = tp * TPART;
#pragma unroll
    for (int u = 0; u < 2; u++) {
      const int rbase = wave * 8 + u * 4;
      const int rloc = rbase + l4;
      const int gb = cb16 ^ (rloc & 15);
      const u16* sh = kh_b + (size_t)(t0 + rloc) * Dd + gb * 8;
      const u16* sl = kl_b + (size_t)(t0 + rloc) * Dd + gb * 8;
      u16* ld = &bufs[0][rbase * 128];
      ASYNC_CP16(sh, ld);
      ASYNC_CP16(sl, ld + 8192);
    }
  }
  __syncthreads();

  for (int tc = 0; tc < TCH; tc++) {
#pragma unroll
    for (int sub = 0; sub < 8; sub++) {  // compile-time sub-stage id
      const bool has_next = (sub < 7) || (tc < TCH - 1);
      const int nsub = (sub + 1) & 7;
      const int ntc = (sub == 7) ? tc + 1 : tc;

      // ---- 1. issue async DMA for next chunk into the other buffer ----
      if (has_next) {
        const int nt0 = tp * TPART + ntc * BN;
        u16* nb = bufs[nsub & 1];
        if (nsub < 4) {  // next is K chunk (hi+lo), d0 = nsub*128
          const int d0 = nsub * 128;
#pragma unroll
          for (int u = 0; u < 2; u++) {
            const int rbase = wave * 8 + u * 4;
            const int rloc = rbase + l4;
            const int gb = cb16 ^ (rloc & 15);
            const u16* sh = kh_b + (size_t)(nt0 + rloc) * Dd + d0 + gb * 8;
            const u16* sl = kl_b + (size_t)(nt0 + rloc) * Dd + d0 + gb * 8;
            u16* ld = &nb[rbase * 128];
            ASYNC_CP16(sh, ld);
            ASYNC_CP16(sl, ld + 8192);
          }
        } else {  // next is V chunk: 128 d-rows x 64 t-cols, nc = nsub-4
          const int nc = nsub - 4;
#pragma unroll
          for (int u = 0; u < 2; u++) {
            const int rbase = wave * 16 + u * 8;
            const int rloc = rbase + vr8;
            const u16* sv = v_b + (size_t)(nc * 128 + rloc) * Tt + nt0 + vcb * 8;
            u16* ld = &nb[rbase * 64];
            ASYNC_CP16(sv, ld);
          }
        }
      }

      // ---- 2. compute on current chunk (buffer parity compile-time) ----
      const u16* bb = bufs[sub & 1];
      if (sub < 4) {  // QK chunk: S += Qh*Kh + Ql*Kh + Qh*Kl over 128 d-cols
        if (sub == 0) {
#pragma unroll
          for (int nt = 0; nt < 4; nt++) s_acc[nt] = (f32x4){0.f, 0.f, 0.f, 0.f};
        }
#pragma unroll
        for (int ks = 0; ks < 4; ks++) {
#pragma unroll
          for (int nt = 0; nt < 4; nt++) {
            const int rr = nt * 16 + l15;
            const int off = rr * 128 + (((ks * 4 + quad) ^ l15)) * 8;  // swizzled read
            short8 bh = *(const short8*)&bb[off];
            short8 bl = *(const short8*)&bb[8192 + off];
            s_acc[nt] = MFMA16(qf_h[sub][ks], bh, s_acc[nt]);
            s_acc[nt] = MFMA16(qf_l[sub][ks], bh, s_acc[nt]);
            s_acc[nt] = MFMA16(qf_h[sub][ks], bl, s_acc[nt]);
          }
        }
        if (sub == 3) {
          // ---- online softmax (C layout: row=quad*4+r, col=nt*16+l15) ----
          float alpha[4], psum[4];
#pragma unroll
          for (int r = 0; r < 4; r++) {
            float v = fmaxf(fmaxf(s_acc[0][r], s_acc[1][r]), fmaxf(s_acc[2][r], s_acc[3][r]));
            v = fmaxf(v, __shfl_xor(v, 1));
            v = fmaxf(v, __shfl_xor(v, 2));
            v = fmaxf(v, __shfl_xor(v, 4));
            v = fmaxf(v, __shfl_xor(v, 8));
            float mn = fmaxf(m_r[r], v);
            alpha[r] = __expf(m_r[r] - mn);
            m_r[r] = mn;
            psum[r] = 0.f;
          }
#pragma unroll
          for (int nt = 0; nt < 4; nt++) {
#pragma unroll
            for (int r = 0; r < 4; r++) {
              float p = __expf(s_acc[nt][r] - m_r[r]);
              psum[r] += p;
              ph[(m0 + quad * 4 + r) * 72 + nt * 16 + l15] = f2bf(p);
            }
          }
#pragma unroll
          for (int r = 0; r < 4; r++) {
            float v = psum[r];
            v += __shfl_xor(v, 1);
            v += __shfl_xor(v, 2);
            v += __shfl_xor(v, 4);
            v += __shfl_xor(v, 8);
            l_r[r] = l_r[r] * alpha[r] + v;
          }
          bool need = (alpha[0] != 1.f) | (alpha[1] != 1.f) | (alpha[2] != 1.f) | (alpha[3] != 1.f);
          if (__any(need)) {
#pragma unroll
            for (int j = 0; j < 32; j++)
#pragma unroll
              for (int r = 0; r < 4; r++) o_acc[j][r] *= alpha[r];
          }
        }
      } else {  // PV chunk: O[nc] += P * V, 128 d-cols; nc COMPILE-TIME
        const int nc = sub - 4;
#pragma unroll
        for (int ks = 0; ks < 2; ks++) {
          const int kk = ks * 32 + quad * 8;
          short8 ap = *(const short8*)&ph[(m0 + l15) * 72 + kk];
#pragma unroll
          for (int nt = 0; nt < 8; nt++) {
            const int rr = nt * 16 + l15;
            const int off = rr * 64 + (((ks * 4 + quad) ^ (l15 & 7))) * 8;  // swizzled read
            short8 bv = *(const short8*)&bb[off];
            o_acc[nc * 8 + nt] = MFMA16(ap, bv, o_acc[nc * 8 + nt]);
          }
        }
      }

      // ---- 3. barrier: drains DMA (vmcnt) + separates buffer reuse ----
      __syncthreads();
    }
  }

  // ---- epilogue: unnormalized partial O (bf16) + m/l stats ----
  const size_t obase = (((size_t)tp * Bb + b) * Ss + s0) * Dd;
#pragma unroll
  for (int j = 0; j < 32; j++) {
    const int col = (j >> 3) * 128 + (j & 7) * 16 + l15;
#pragma unroll
    for (int r = 0; r < 4; r++) {
      const int row = m0 + quad * 4 + r;
      opart[obase + (size_t)row * Dd + col] = f2bf(o_acc[j][r]);
    }
  }
  if (l15 == 0) {
    const size_t sbase = ((size_t)tp * Bb + b) * Ss + s0;
#pragma unroll
    for (int r = 0; r < 4; r++) {
      const int row = m0 + quad * 4 + r;
      mpart[sbase + row] = m_r[r];
      lpart[sbase + row] = l_r[r];
    }
  }
}

// Merge TP partitions: ctx = sum_p e^{m_p-M} O_p / sum_p e^{m_p-M} l_p
__global__ void combine_kernel(const u16* __restrict__ opart,
                               const float* __restrict__ mpart,
                               const float* __restrict__ lpart,
                               u16* __restrict__ ctx) {
  const int idx = blockIdx.x * blockDim.x + threadIdx.x;  // vec8 index
  const int vpr = Dd / 8;
  const int row = idx / vpr;  // b*Ss + s
  const int dv = (idx % vpr) * 8;
  float mv[TP], mM = -INFINITY;
#pragma unroll
  for (int p = 0; p < TP; p++) {
    mv[p] = mpart[(size_t)p * Bb * Ss + row];
    mM = fmaxf(mM, mv[p]);
  }
  float w[TP], denom = 0.f;
#pragma unroll
  for (int p = 0; p < TP; p++) {
    float e = __expf(mv[p] - mM);
    w[p] = e;
    denom += e * lpart[(size_t)p * Bb * Ss + row];
  }
  const float inv = 1.0f / denom;
  float acc[8];
#pragma unroll
  for (int e = 0; e < 8; e++) acc[e] = 0.f;
#pragma unroll
  for (int p = 0; p < TP; p++) {
    uint4 raw = *(const uint4*)&opart[(size_t)p * Bb * Ss * Dd + (size_t)row * Dd + dv];
    const u16* u = (const u16*)&raw;
#pragma unroll
    for (int e = 0; e < 8; e++) acc[e] += w[p] * bf2f(u[e]);
  }
  u16 outv[8];
#pragma unroll
  for (int e = 0; e < 8; e++) outv[e] = f2bf(acc[e] * inv);
  *(uint4*)&ctx[(size_t)row * Dd + dv] = *(const uint4*)outv;
}

// out[8192,512] = ctx_bf16 @ d4 + d5 ; 128x128 tile, 256 thr, wave = 64x64
__global__ __launch_bounds__(256, 2)
void proj_kernel(const u16* __restrict__ ctx,
                 const u16* __restrict__ d4t,  // [n][k]
                 const float* __restrict__ d5,
                 float* __restrict__ out) {
  __shared__ u16 a_lds[128 * 40], b_lds[128 * 40];
  const int tid = threadIdx.x;
  const int wave = tid >> 6, lane = tid & 63, quad = lane >> 4, l15 = lane & 15;
  const int m0w = (wave & 1) * 64, n0w = (wave >> 1) * 64;
  const int bm = blockIdx.x, bn = blockIdx.y;
  f32x4 acc[4][4];
#pragma unroll
  for (int i = 0; i < 4; i++)
#pragma unroll
    for (int j = 0; j < 4; j++) acc[i][j] = (f32x4){0.f, 0.f, 0.f, 0.f};

  const int srow = tid >> 2, scol = (tid & 3) * 8;
  for (int kt = 0; kt < 16; kt++) {
    const int k0 = kt * 32;
    __syncthreads();
#pragma unroll
    for (int pass = 0; pass < 2; pass++) {
      const int row = srow + pass * 64;
      *(uint4*)&a_lds[row * 40 + scol] =
          *(const uint4*)&ctx[(size_t)(bm * 128 + row) * Dd + k0 + scol];
      *(uint4*)&b_lds[row * 40 + scol] =
          *(const uint4*)&d4t[(size_t)(bn * 128 + row) * Dd + k0 + scol];
    }
    __syncthreads();
    short8 af[4], bfr[4];
#pragma unroll
    for (int i = 0; i < 4; i++)
      af[i] = *(const short8*)&a_lds[(m0w + 16 * i + l15) * 40 + quad * 8];
#pragma unroll
    for (int j = 0; j < 4; j++)
      bfr[j] = *(const short8*)&b_lds[(n0w + 16 * j + l15) * 40 + quad * 8];
#pragma unroll
    for (int i = 0; i < 4; i++)
#pragma unroll
      for (int j = 0; j < 4; j++) acc[i][j] = MFMA16(af[i], bfr[j], acc[i][j]);
  }
#pragma unroll
  for (int j = 0; j < 4; j++) {
    const int colg = bn * 128 + n0w + 16 * j + l15;
    const float bias = d5[colg];
#pragma unroll
    for (int i = 0; i < 4; i++) {
#pragma unroll
      for (int r = 0; r < 4; r++) {
        const int rowg = bm * 128 + m0w + 16 * i + quad * 4 + r;
        out[(size_t)rowg * 512 + colg] = acc[i][j][r] + bias;
      }
    }
  }
}

extern "C" void kernel_launch(void* const* d_in, const int* in_sizes, int n_in,
                              void* d_out, int out_size, void* d_ws, size_t ws_size,
                              hipStream_t stream) {
  (void)in_sizes; (void)n_in; (void)out_size; (void)ws_size;
  const float* d1 = (const float*)d_in[0];
  const float* d2 = (const float*)d_in[1];
  const float* d3 = (const float*)d_in[2];
  const float* d4 = (const float*)d_in[3];
  const float* d5 = (const float*)d_in[4];
  float* out = (float*)d_out;
  char* ws = (char*)d_ws;

  u16* qh_g = (u16*)(ws + O_QH);
  u16* ql_g = (u16*)(ws + O_QL);
  u16* d2th = (u16*)(ws + O_D2TH);
  u16* d2tl = (u16*)(ws + O_D2TL);
  u16* d3t  = (u16*)(ws + O_D3T);
  u16* d4t  = (u16*)(ws + O_D4T);
  u16* ctx  = (u16*)(ws + O_CTX);
  u16* opart = (u16*)(ws + O_OP);
  float* mpart = (float*)(ws + O_MP);
  float* lpart = (float*)(ws + O_LP);

  prep_kernel<<<12544, 256, 0, stream>>>(d1, d2, d3, d4, qh_g, ql_g, d2th, d2tl, d3t, d4t);
  // grid (8, 32): x = (b<<2)|tp (XCD-pinned partition), y = s-block
  flash_part_kernel<<<dim3(8, 32), 512, 0, stream>>>(qh_g, ql_g, d2th, d2tl, d3t,
                                                     opart, mpart, lpart);
  combine_kernel<<<(Bb * Ss * Dd / 8) / 256, 256, 0, stream>>>(opart, mpart, lpart, ctx);
  proj_kernel<<<dim3(64, 4), 256, 0, stream>>>(ctx, d4t, d5, out);
}